// Round 8
// baseline (191.641 us; speedup 1.0000x reference)
//
#include <hip/hip_runtime.h>
#include <math.h>

#define B_  4096
#define C_  64
#define LQ_ 32
#define D_  128
#define H_  192

typedef __attribute__((ext_vector_type(8))) short bf16x8;
typedef __attribute__((ext_vector_type(4))) float f32x4;

#define KEEP(x) asm volatile("" : "+v"(x))

__device__ inline unsigned cvt_pk_bf16(float lo, float hi) {
    unsigned r;
    asm("v_cvt_pk_bf16_f32 %0, %1, %2" : "=v"(r) : "v"(lo), "v"(hi));
    return r;
}
__device__ inline short f2b(float x) { return (short)(cvt_pk_bf16(x, x) & 0xffff); }
__device__ inline float sigm(float x) { return 1.f / (1.f + __expf(-x)); }

// Raw barrier: waits LDS ops only; leaves global loads in flight (T4).
__device__ inline void wg_barrier() {
    asm volatile("s_waitcnt lgkmcnt(0)" ::: "memory");
    __builtin_amdgcn_s_barrier();
    asm volatile("" ::: "memory");
}

// ---------------------------------------------------------------------------
// Prep: transpose + convert weights to bf16.
// ---------------------------------------------------------------------------
__global__ __launch_bounds__(256) void prep_kernel(
    const float* __restrict__ W1, const float* __restrict__ W2,
    const float* __restrict__ Wx, const float* __restrict__ Wh,
    short* __restrict__ W1T, short* __restrict__ W2T, short* __restrict__ WTl)
{
    int idx = blockIdx.x * 256 + threadIdx.x;   // 0 .. 131071
    if (idx < 192 * 256) {
        int j = idx >> 8, k = idx & 255;
        W1T[idx] = f2b(W1[k * H_ + j]);
    }
    if (idx < 128 * 192) {
        int j = idx / 192, k = idx - j * 192;
        W2T[idx] = f2b(W2[k * D_ + j]);
    }
    if (idx < 512 * 256) {
        int p = idx >> 8, k = idx & 255;
        int w = p >> 6, g = (p >> 4) & 3, jj = p & 15;
        int jo = g * 128 + w * 16 + jj;
        float v = (k < 128) ? Wx[k * 512 + jo] : Wh[(k - 128) * 512 + jo];
        WTl[idx] = f2b(v);
    }
}

// ---------------------------------------------------------------------------
// Table encoder v8: ONE barrier per body (LSTM-like pipeline).
// Body(c) = [GEMM1 on flat[c] -> h-write -> stage flat[c+1] + issue(c+3)
//            -> BARRIER -> GEMM2 on h[c] + masked csum].
// Per-b reductions deferred to a single epilogue (no mid-loop barriers).
// 1024 blocks x 256 thr (4 waves), 4 b's/block, 16-row chunks.
// flat_s and h_s double-buffered; depth-2 prefetch (pf0=even, pf1=odd).
// ---------------------------------------------------------------------------
__global__ __launch_bounds__(256, 2)
void table_kernel(
    const float* __restrict__ header, const float* __restrict__ tword,
    const float* __restrict__ masks, const int* __restrict__ num_cols,
    const short* __restrict__ W1T, const float* __restrict__ b1,
    const short* __restrict__ W2T, const float* __restrict__ b2,
    float* __restrict__ te_out)
{
    const int bb0 = blockIdx.x * 4;
    const int tid = threadIdx.x;
    const int w   = tid >> 6;      // 0..3: column-group wave
    const int l   = tid & 63;
    const int lg  = l >> 4;
    const int ln  = l & 15;

    __shared__ __align__(16) short flat_s[2][16 * 256];  // 2 x 8 KB, swizzled
    __shared__ __align__(16) short h_s2[2][16 * 192];    // 2 x 6 KB, swizzled
    __shared__ float msk_s[4][64];                       // 1 KB
    __shared__ float ncol_s[4];
    __shared__ float csum_s[4][128];                     // 2 KB
    __shared__ float redq[2][4];

    // ---- resident weights (swapped-operand layout), pinned
    bf16x8 bw1[3][8];
    float bias1[3][4];
    #pragma unroll
    for (int ct = 0; ct < 3; ++ct) {
        int j = w * 48 + ct * 16 + ln;
        #pragma unroll
        for (int ks = 0; ks < 8; ++ks)
            bw1[ct][ks] = *(const bf16x8*)&W1T[j * 256 + ks * 32 + lg * 8];
        #pragma unroll
        for (int reg = 0; reg < 4; ++reg)
            bias1[ct][reg] = b1[w * 48 + ct * 16 + lg * 4 + reg];
    }
    bf16x8 bw2[2][6];
    float bias2[2][4];
    #pragma unroll
    for (int ct = 0; ct < 2; ++ct) {
        int j = w * 32 + ct * 16 + ln;
        #pragma unroll
        for (int ks = 0; ks < 6; ++ks)
            bw2[ct][ks] = *(const bf16x8*)&W2T[j * 192 + ks * 32 + lg * 8];
        #pragma unroll
        for (int reg = 0; reg < 4; ++reg)
            bias2[ct][reg] = b2[w * 32 + ct * 16 + lg * 4 + reg];
    }
    #pragma unroll
    for (int ct = 0; ct < 3; ++ct) {
        #pragma unroll
        for (int ks = 0; ks < 8; ++ks) KEEP(bw1[ct][ks]);
        #pragma unroll
        for (int reg = 0; reg < 4; ++reg) KEEP(bias1[ct][reg]);
    }
    #pragma unroll
    for (int ct = 0; ct < 2; ++ct) {
        #pragma unroll
        for (int ks = 0; ks < 6; ++ks) KEEP(bw2[ct][ks]);
        #pragma unroll
        for (int reg = 0; reg < 4; ++reg) KEEP(bias2[ct][reg]);
    }

    // ---- preload masks + num_cols for the 4 b's
    ((float*)msk_s)[tid] = masks[(size_t)bb0 * C_ + tid];
    if (tid < 4) ncol_s[tid] = (float)num_cols[bb0 + tid];

    // ---- depth-2 prefetch: 4 float4/thread = one 16-row fp32 chunk
    float4 pf0[4], pf1[4];
    auto issue = [&](int cc, float4 (&dst)[4]) {
        int b    = bb0 + (cc >> 2);
        int row0 = (cc & 3) * 16;
        #pragma unroll
        for (int i = 0; i < 4; ++i) {
            int idx = i * 256 + tid;         // 0..1023 float4 slots
            int r   = idx >> 6;              // 0..15
            int c   = idx & 63;
            const float* src = (c < 32)
                ? &header[((size_t)b * C_ + row0 + r) * D_ + c * 4]
                : &tword [((size_t)b * C_ + row0 + r) * D_ + (c - 32) * 4];
            dst[i] = *(const float4*)src;
        }
    };
    auto stage = [&](float4 (&pfc)[4], char* fbuf) {
        #pragma unroll
        for (int i = 0; i < 4; ++i) {
            int idx = i * 256 + tid;
            int r   = idx >> 6;
            int c   = idx & 63;
            uint2 p;
            p.x = cvt_pk_bf16(pfc[i].x, pfc[i].y);
            p.y = cvt_pk_bf16(pfc[i].z, pfc[i].w);
            *(uint2*)(fbuf + r * 512 + ((c * 8) ^ ((r & 7) << 4))) = p;
        }
    };

    issue(0, pf0);
    issue(1, pf1);
    __syncthreads();               // masks/ncol visible (drains prologue loads, ok)

    stage(pf0, (char*)flat_s[0]);  // flat[0]
    issue(2, pf0);
    wg_barrier();                  // flat[0] ready

    float csum[2][4] = {{0.f, 0.f, 0.f, 0.f}, {0.f, 0.f, 0.f, 0.f}};
    const int row = ln;
    const int swz = (ln & 7) << 4;

    auto body = [&](int cc, float4 (&pfN)[4], bool doStage) {
        char* fbuf = (char*)flat_s[cc & 1];
        char* hbuf = (char*)h_s2[cc & 1];
        const int bi = cc >> 2;

        // ---- GEMM1 swapped: D[j][r] on flat[cc]
        {
            f32x4 acc[3];
            #pragma unroll
            for (int ct = 0; ct < 3; ++ct)
                acc[ct] = (f32x4){bias1[ct][0], bias1[ct][1], bias1[ct][2], bias1[ct][3]};
            #pragma unroll
            for (int ks = 0; ks < 8; ++ks) {
                bf16x8 a = *(const bf16x8*)(fbuf + row * 512 + ((ks * 64 + lg * 16) ^ swz));
                #pragma unroll
                for (int ct = 0; ct < 3; ++ct)
                    acc[ct] = __builtin_amdgcn_mfma_f32_16x16x32_bf16(bw1[ct][ks], a, acc[ct], 0, 0, 0);
            }
            #pragma unroll
            for (int ct = 0; ct < 3; ++ct) {
                int col0 = w * 48 + ct * 16 + lg * 4;
                uint2 hp;
                hp.x = cvt_pk_bf16(fmaxf(acc[ct][0], 0.f), fmaxf(acc[ct][1], 0.f));
                hp.y = cvt_pk_bf16(fmaxf(acc[ct][2], 0.f), fmaxf(acc[ct][3], 0.f));
                *(uint2*)(hbuf + row * 384 + ((col0 * 2) ^ swz)) = hp;
            }
        }

        // ---- stage flat[cc+1] + refill its pf slot (pre-barrier)
        if (doStage) {
            stage(pfN, (char*)flat_s[(cc + 1) & 1]);
            if (cc + 3 < 16) issue(cc + 3, pfN);
        }

        wg_barrier();   // orders: h[cc] ready AND flat[cc+1] ready

        // ---- GEMM2 swapped on h[cc] + fused mask*column-sum
        {
            f32x4 acc2[2];
            #pragma unroll
            for (int ct = 0; ct < 2; ++ct)
                acc2[ct] = (f32x4){bias2[ct][0], bias2[ct][1], bias2[ct][2], bias2[ct][3]};
            #pragma unroll
            for (int ks = 0; ks < 6; ++ks) {
                bf16x8 a = *(const bf16x8*)(hbuf + row * 384 + ((ks * 64 + lg * 16) ^ swz));
                #pragma unroll
                for (int ct = 0; ct < 2; ++ct)
                    acc2[ct] = __builtin_amdgcn_mfma_f32_16x16x32_bf16(bw2[ct][ks], a, acc2[ct], 0, 0, 0);
            }
            float m = msk_s[bi][(cc & 3) * 16 + ln];
            #pragma unroll
            for (int ct = 0; ct < 2; ++ct)
                #pragma unroll
                for (int reg = 0; reg < 4; ++reg)
                    csum[ct][reg] = fmaf(fmaxf(acc2[ct][reg], 0.f), m, csum[ct][reg]);
        }

        // ---- end of b: ln-butterfly, flush to LDS (NO barrier), reset
        if ((cc & 3) == 3) {
            #pragma unroll
            for (int s = 1; s < 16; s <<= 1)
                #pragma unroll
                for (int ct = 0; ct < 2; ++ct)
                    #pragma unroll
                    for (int reg = 0; reg < 4; ++reg)
                        csum[ct][reg] += __shfl_xor(csum[ct][reg], s, 64);
            if (ln == 0) {
                #pragma unroll
                for (int ct = 0; ct < 2; ++ct)
                    #pragma unroll
                    for (int reg = 0; reg < 4; ++reg)
                        csum_s[bi][w * 32 + ct * 16 + lg * 4 + reg] = csum[ct][reg];
            }
            #pragma unroll
            for (int ct = 0; ct < 2; ++ct)
                #pragma unroll
                for (int reg = 0; reg < 4; ++reg)
                    csum[ct][reg] = 0.f;
        }
    };

    #pragma unroll 1
    for (int p = 0; p < 8; ++p) {
        body(p * 2,     pf1, true);             // stages odd chunk from pf1
        body(p * 2 + 1, pf0, p * 2 + 2 < 16);   // stages even chunk from pf0
    }

    // ---- epilogue: all 4 b's at once (2 barriers total)
    __syncthreads();
    float vv[4];
    if (tid < 128) {
        #pragma unroll
        for (int bi = 0; bi < 4; ++bi) {
            float v = csum_s[bi][tid] / ncol_s[bi];
            vv[bi] = v;
            float s2 = v * v;
            #pragma unroll
            for (int sh = 1; sh < 64; sh <<= 1) s2 += __shfl_xor(s2, sh, 64);
            if (l == 0) redq[w][bi] = s2;
        }
    }
    __syncthreads();
    if (tid < 128) {
        #pragma unroll
        for (int bi = 0; bi < 4; ++bi) {
            float inv = rsqrtf(fmaxf(redq[0][bi] + redq[1][bi], 1e-12f));
            te_out[(size_t)(bb0 + bi) * D_ + tid] = vv[bi] * inv;
        }
    }
}

// ---------------------------------------------------------------------------
// LSTM (round-5 version): 256 blocks x 512 threads, 16 rows/block,
// depth-1 x prefetch, raw barriers, weights pinned resident.
// ---------------------------------------------------------------------------
__global__ __launch_bounds__(512) __attribute__((amdgpu_waves_per_eu(1, 2)))
void lstm_kernel(
    const float* __restrict__ q, const int* __restrict__ lengths,
    const short* __restrict__ WTl, const float* __restrict__ bl,
    float* __restrict__ qe_out)
{
    const int tid = threadIdx.x;
    const int b0  = blockIdx.x * 16;
    const int w   = tid >> 6;
    const int l   = tid & 63;
    const int lg  = l >> 4;
    const int ln  = l & 15;       // batch row within block
    const int d0  = w * 16 + lg * 4;

    __shared__ __align__(16) short xh[2][16 * 256];  // 2 x 8 KB, swizzled
    __shared__ float red8[8][16];

    bf16x8 wf[4][8];
    #pragma unroll
    for (int g = 0; g < 4; ++g)
        #pragma unroll
        for (int ks = 0; ks < 8; ++ks)
            wf[g][ks] = *(const bf16x8*)&WTl[(w * 64 + g * 16 + ln) * 256 + ks * 32 + lg * 8];
    float bias[4][4];
    #pragma unroll
    for (int g = 0; g < 4; ++g)
        #pragma unroll
        for (int reg = 0; reg < 4; ++reg)
            bias[g][reg] = bl[g * 128 + d0 + reg];
    #pragma unroll
    for (int g = 0; g < 4; ++g) {
        #pragma unroll
        for (int ks = 0; ks < 8; ++ks) KEEP(wf[g][ks]);
        #pragma unroll
        for (int reg = 0; reg < 4; ++reg) KEEP(bias[g][reg]);
    }

    float creg[4] = {0.f, 0.f, 0.f, 0.f};
    float hreg[4] = {0.f, 0.f, 0.f, 0.f};
    const int len = lengths[b0 + ln];
    const int sr = tid >> 5, sc = tid & 31;

    // prefetch x_0
    float4 qv = *(const float4*)&q[((size_t)(b0 + sr) * LQ_ + 0) * D_ + sc * 4];

    for (int t = 0; t < LQ_; ++t) {
        char* buf = (char*)xh[t & 1];
        // stage x_t from prefetched regs
        uint2 px; px.x = cvt_pk_bf16(qv.x, qv.y); px.y = cvt_pk_bf16(qv.z, qv.w);
        *(uint2*)(buf + sr * 512 + ((sc * 8) ^ ((sr & 7) << 4))) = px;
        // write h(t-1)
        uint2 ph; ph.x = cvt_pk_bf16(hreg[0], hreg[1]); ph.y = cvt_pk_bf16(hreg[2], hreg[3]);
        *(uint2*)(buf + ln * 512 + ((256 + d0 * 2) ^ ((ln & 7) << 4))) = ph;
        // prefetch x_{t+1}: stays in flight across the raw barrier + MFMA
        if (t + 1 < LQ_)
            qv = *(const float4*)&q[((size_t)(b0 + sr) * LQ_ + (t + 1)) * D_ + sc * 4];
        wg_barrier();

        f32x4 acc[4];
        #pragma unroll
        for (int g = 0; g < 4; ++g)
            acc[g] = (f32x4){bias[g][0], bias[g][1], bias[g][2], bias[g][3]};
        #pragma unroll
        for (int ks = 0; ks < 8; ++ks) {
            bf16x8 xf = *(const bf16x8*)(buf + ln * 512 + ((ks * 64 + lg * 16) ^ ((ln & 7) << 4)));
            #pragma unroll
            for (int g = 0; g < 4; ++g)
                acc[g] = __builtin_amdgcn_mfma_f32_16x16x32_bf16(wf[g][ks], xf, acc[g], 0, 0, 0);
        }

        bool live = (t < len);
        #pragma unroll
        for (int reg = 0; reg < 4; ++reg) {
            float iv = sigm(acc[0][reg]);
            float fv = sigm(acc[1][reg]);
            float gv = fmaxf(acc[2][reg], 0.f);
            float ov = sigm(acc[3][reg]);
            float cn = fmaf(fv, creg[reg], iv * gv);
            float hn = ov * fmaxf(cn, 0.f);
            if (live) { creg[reg] = cn; hreg[reg] = hn; }
        }
    }

    // l2norm per batch row
    float sq = 0.f;
    #pragma unroll
    for (int reg = 0; reg < 4; ++reg) sq = fmaf(hreg[reg], hreg[reg], sq);
    sq += __shfl_xor(sq, 16, 64);
    sq += __shfl_xor(sq, 32, 64);
    if (l < 16) red8[w][ln] = sq;
    wg_barrier();
    float tot = 0.f;
    #pragma unroll
    for (int ww = 0; ww < 8; ++ww) tot += red8[ww][ln];
    float inv = rsqrtf(fmaxf(tot, 1e-12f));
    float4 o;
    o.x = hreg[0] * inv; o.y = hreg[1] * inv; o.z = hreg[2] * inv; o.w = hreg[3] * inv;
    *(float4*)&qe_out[(size_t)(b0 + ln) * D_ + d0] = o;
}

// ---------------------------------------------------------------------------
// Loss: 64 blocks x 64 threads, 1 sample per thread.
// ---------------------------------------------------------------------------
__global__ __launch_bounds__(64) void loss_kernel(
    const float* __restrict__ te, const float* __restrict__ qe,
    const float* __restrict__ labels, float* __restrict__ partial)
{
    const int tid = threadIdx.x;
    const int b   = blockIdx.x * 64 + tid;
    float dsum = 0.f;
    #pragma unroll 8
    for (int k4 = 0; k4 < 32; ++k4) {
        float4 a = *(const float4*)&qe[(size_t)b * D_ + k4 * 4];
        float4 c = *(const float4*)&te[(size_t)b * D_ + k4 * 4];
        float dx = a.x - c.x, dy = a.y - c.y, dz = a.z - c.z, dw = a.w - c.w;
        dsum += dx * dx + dy * dy + dz * dz + dw * dw;
    }
    float lab = labels[b];
    float ds  = sqrtf(dsum);
    float ml  = fmaxf(0.f, 1.f - ds);
    float loss = lab * dsum + (1.f - lab) * ml * ml;
    #pragma unroll
    for (int s = 32; s > 0; s >>= 1) loss += __shfl_xor(loss, s, 64);
    if (tid == 0) partial[blockIdx.x] = loss;
}

__global__ void final_kernel(const float* __restrict__ partial, float* __restrict__ out)
{
    const int tid = threadIdx.x;   // 64 threads
    float v = partial[tid];
    #pragma unroll
    for (int s = 32; s > 0; s >>= 1) v += __shfl_xor(v, s, 64);
    if (tid == 0) out[0] = 0.5f * v / (float)B_;
}

// ---------------------------------------------------------------------------
extern "C" void kernel_launch(void* const* d_in, const int* in_sizes, int n_in,
                              void* d_out, int out_size, void* d_ws, size_t ws_size,
                              hipStream_t stream)
{
    const float* q      = (const float*)d_in[0];
    const int*   qlen   = (const int*)d_in[1];
    const float* header = (const float*)d_in[2];
    const float* tword  = (const float*)d_in[3];
    const int*   ncols  = (const int*)d_in[4];
    const float* masks  = (const float*)d_in[5];
    const float* labels = (const float*)d_in[6];
    const float* W1     = (const float*)d_in[7];
    const float* b1     = (const float*)d_in[8];
    const float* W2     = (const float*)d_in[9];
    const float* b2     = (const float*)d_in[10];
    const float* Wx     = (const float*)d_in[11];
    const float* Wh     = (const float*)d_in[12];
    const float* bl     = (const float*)d_in[13];
    float* out = (float*)d_out;

    float* te      = (float*)d_ws;
    float* qe      = te + (size_t)B_ * D_;
    float* partial = qe + (size_t)B_ * D_;
    short* W1T     = (short*)(partial + 64);          // 192*256
    short* W2T     = W1T + 192 * 256;                 // 128*192
    short* WTl     = W2T + 128 * 192;                 // 512*256

    prep_kernel<<<512, 256, 0, stream>>>(W1, W2, Wx, Wh, W1T, W2T, WTl);
    table_kernel<<<B_ / 4, 256, 0, stream>>>(header, tword, masks, ncols, W1T, b1, W2T, b2, te);
    lstm_kernel<<<B_ / 16, 512, 0, stream>>>(q, qlen, WTl, bl, qe);
    loss_kernel<<<B_ / 64, 64, 0, stream>>>(te, qe, labels, partial);
    final_kernel<<<1, 64, 0, stream>>>(partial, out);
}

// Round 9
// 166.829 us; speedup vs baseline: 1.1487x; 1.1487x over previous
//
#include <hip/hip_runtime.h>
#include <math.h>

#define B_  4096
#define C_  64
#define LQ_ 32
#define D_  128
#define H_  192

typedef __attribute__((ext_vector_type(8))) short bf16x8;
typedef __attribute__((ext_vector_type(4))) float f32x4;

#define KEEP(x) asm volatile("" : "+v"(x))

__device__ inline unsigned cvt_pk_bf16(float lo, float hi) {
    unsigned r;
    asm("v_cvt_pk_bf16_f32 %0, %1, %2" : "=v"(r) : "v"(lo), "v"(hi));
    return r;
}
__device__ inline short f2b(float x) { return (short)(cvt_pk_bf16(x, x) & 0xffff); }
__device__ inline float sigm(float x) { return 1.f / (1.f + __expf(-x)); }

// Raw barrier: waits LDS ops only; leaves global loads / LDS-DMA in flight.
__device__ inline void wg_barrier() {
    asm volatile("s_waitcnt lgkmcnt(0)" ::: "memory");
    __builtin_amdgcn_s_barrier();
    asm volatile("" ::: "memory");
}
// Barrier that also waits the LDS-DMA (end of body: next chunk landed).
__device__ inline void wg_barrier_vm() {
    asm volatile("s_waitcnt vmcnt(0) lgkmcnt(0)" ::: "memory");
    __builtin_amdgcn_s_barrier();
    asm volatile("" ::: "memory");
}

// ---------------------------------------------------------------------------
// Prep: transpose + convert weights to bf16.
// ---------------------------------------------------------------------------
__global__ __launch_bounds__(256) void prep_kernel(
    const float* __restrict__ W1, const float* __restrict__ W2,
    const float* __restrict__ Wx, const float* __restrict__ Wh,
    short* __restrict__ W1T, short* __restrict__ W2T, short* __restrict__ WTl)
{
    int idx = blockIdx.x * 256 + threadIdx.x;   // 0 .. 131071
    if (idx < 192 * 256) {
        int j = idx >> 8, k = idx & 255;
        W1T[idx] = f2b(W1[k * H_ + j]);
    }
    if (idx < 128 * 192) {
        int j = idx / 192, k = idx - j * 192;
        W2T[idx] = f2b(W2[k * D_ + j]);
    }
    if (idx < 512 * 256) {
        int p = idx >> 8, k = idx & 255;
        int w = p >> 6, g = (p >> 4) & 3, jj = p & 15;
        int jo = g * 128 + w * 16 + jj;
        float v = (k < 128) ? Wx[k * 512 + jo] : Wh[(k - 128) * 512 + jo];
        WTl[idx] = f2b(v);
    }
}

// ---------------------------------------------------------------------------
// Table encoder v9: register diet -> 2 blocks/CU co-resident.
//  - global_load_lds DMAs fp32 chunk directly to LDS (no pf regs, no stage VALU)
//    with pre-swizzled SOURCE addresses (linear dest + swz read).
//  - only W1+bias1 pinned (108 regs); W2/bias2 streamed from L2 at body start.
//  - body: issue W2 -> issue DMA(c+1) -> GEMM1(bf16-ify frags from fp32 LDS)
//          -> wg_barrier -> GEMM2+csum -> [every 4th: reduce/l2norm/store]
//          -> vmcnt(0)+barrier.
// 1024 blocks x 256 thr (4 waves), 4 b's/block, 16-row chunks.
// ---------------------------------------------------------------------------
__global__ __launch_bounds__(256, 2)
void table_kernel(
    const float* __restrict__ header, const float* __restrict__ tword,
    const float* __restrict__ masks, const int* __restrict__ num_cols,
    const short* __restrict__ W1T, const float* __restrict__ b1,
    const short* __restrict__ W2T, const float* __restrict__ b2,
    float* __restrict__ te_out)
{
    const int bb0 = blockIdx.x * 4;
    const int tid = threadIdx.x;
    const int w   = tid >> 6;      // 0..3: column-group wave
    const int l   = tid & 63;
    const int lg  = l >> 4;
    const int ln  = l & 15;

    __shared__ __align__(16) float flat32[2][16 * 256];  // 2 x 16 KB (fp32!)
    __shared__ __align__(16) short h_s[16 * 192];        // 6 KB bf16, swizzled
    __shared__ float msk_s[4][64];                       // 1 KB
    __shared__ float ncol_s[4];
    __shared__ float redv[128];
    __shared__ float redq[2];

    // ---- resident W1 + bias1 only (108 regs pinned)
    bf16x8 bw1[3][8];
    float  bias1[3][4];
    #pragma unroll
    for (int ct = 0; ct < 3; ++ct) {
        int j = w * 48 + ct * 16 + ln;
        #pragma unroll
        for (int ks = 0; ks < 8; ++ks)
            bw1[ct][ks] = *(const bf16x8*)&W1T[j * 256 + ks * 32 + lg * 8];
        #pragma unroll
        for (int reg = 0; reg < 4; ++reg)
            bias1[ct][reg] = b1[w * 48 + ct * 16 + lg * 4 + reg];
    }
    #pragma unroll
    for (int ct = 0; ct < 3; ++ct) {
        #pragma unroll
        for (int ks = 0; ks < 8; ++ks) KEEP(bw1[ct][ks]);
        #pragma unroll
        for (int reg = 0; reg < 4; ++reg) KEEP(bias1[ct][reg]);
    }

    // ---- preload masks + num_cols for the 4 b's
    ((float*)msk_s)[tid] = masks[(size_t)bb0 * C_ + tid];
    if (tid < 4) ncol_s[tid] = (float)num_cols[bb0 + tid];

    // ---- async DMA stage: chunk = 16 rows x 1 KB; wave w issues rows w*4..+3.
    //      LDS dest is linear; source address carries the inverse swizzle so
    //      the read-side XOR ((row&7)<<4 on bytes) sees conflict-free rows.
    auto stage_issue = [&](int cc, int buf) {
        int b    = bb0 + (cc >> 2);
        int row0 = (cc & 3) * 16;
        #pragma unroll
        for (int i = 0; i < 4; ++i) {
            int r = w * 4 + i;                          // wave-uniform
            int p = ((l * 16) ^ ((r & 7) << 4)) >> 2;   // f32 col, mult of 4
            const float* srcp = (p < 128)
                ? header + ((size_t)b * C_ + row0 + r) * D_ + p
                : tword  + ((size_t)b * C_ + row0 + r) * D_ + (p - 128);
            __builtin_amdgcn_global_load_lds(
                (const __attribute__((address_space(1))) unsigned*)srcp,
                (__attribute__((address_space(3))) unsigned*)&flat32[buf][r * 256],
                16, 0, 0);
        }
    };

    stage_issue(0, 0);
    __syncthreads();          // chunk0 landed (full drain) + masks visible

    float csum[2][4] = {{0.f, 0.f, 0.f, 0.f}, {0.f, 0.f, 0.f, 0.f}};
    const int swz = (ln & 7) << 4;

    for (int cc = 0; cc < 16; ++cc) {
        const int bi  = cc >> 2;
        const int cur = cc & 1;

        // ---- issue W2 frags + bias2 first (oldest in vmem FIFO), then DMA
        bf16x8 w2f[2][6];
        #pragma unroll
        for (int ct = 0; ct < 2; ++ct)
            #pragma unroll
            for (int ks = 0; ks < 6; ++ks)
                w2f[ct][ks] = *(const bf16x8*)&W2T[(w * 32 + ct * 16 + ln) * 192 + ks * 32 + lg * 8];
        float4 b2v[2];
        #pragma unroll
        for (int ct = 0; ct < 2; ++ct)
            b2v[ct] = *(const float4*)&b2[w * 32 + ct * 16 + lg * 4];
        if (cc + 1 < 16) stage_issue(cc + 1, cur ^ 1);

        // ---- GEMM1: bf16-ify B-frags from fp32 LDS, 24 MFMA vs resident W1
        {
            const char* fb = (const char*)flat32[cur] + ln * 1024;
            f32x4 acc[3];
            #pragma unroll
            for (int ct = 0; ct < 3; ++ct)
                acc[ct] = (f32x4){bias1[ct][0], bias1[ct][1], bias1[ct][2], bias1[ct][3]};
            #pragma unroll
            for (int ks = 0; ks < 8; ++ks) {
                int base = ks * 128 + lg * 32;
                f32x4 a0 = *(const f32x4*)(fb + ((base)      ^ swz));
                f32x4 a1 = *(const f32x4*)(fb + ((base + 16) ^ swz));
                unsigned uu[4];
                uu[0] = cvt_pk_bf16(a0[0], a0[1]);
                uu[1] = cvt_pk_bf16(a0[2], a0[3]);
                uu[2] = cvt_pk_bf16(a1[0], a1[1]);
                uu[3] = cvt_pk_bf16(a1[2], a1[3]);
                bf16x8 bfrag = *(bf16x8*)uu;
                #pragma unroll
                for (int ct = 0; ct < 3; ++ct)
                    acc[ct] = __builtin_amdgcn_mfma_f32_16x16x32_bf16(bw1[ct][ks], bfrag, acc[ct], 0, 0, 0);
            }
            #pragma unroll
            for (int ct = 0; ct < 3; ++ct) {
                int col0 = w * 48 + ct * 16 + lg * 4;
                uint2 hp;
                hp.x = cvt_pk_bf16(fmaxf(acc[ct][0], 0.f), fmaxf(acc[ct][1], 0.f));
                hp.y = cvt_pk_bf16(fmaxf(acc[ct][2], 0.f), fmaxf(acc[ct][3], 0.f));
                *(uint2*)((char*)h_s + ln * 384 + ((col0 * 2) ^ swz)) = hp;
            }
        }
        wg_barrier();   // h ready; DMA stays in flight

        // ---- GEMM2 (streamed W2) + fused mask*column-sum
        {
            f32x4 acc2[2];
            #pragma unroll
            for (int ct = 0; ct < 2; ++ct)
                acc2[ct] = (f32x4){b2v[ct].x, b2v[ct].y, b2v[ct].z, b2v[ct].w};
            #pragma unroll
            for (int ks = 0; ks < 6; ++ks) {
                bf16x8 a = *(const bf16x8*)((char*)h_s + ln * 384 + ((ks * 64 + lg * 16) ^ swz));
                #pragma unroll
                for (int ct = 0; ct < 2; ++ct)
                    acc2[ct] = __builtin_amdgcn_mfma_f32_16x16x32_bf16(w2f[ct][ks], a, acc2[ct], 0, 0, 0);
            }
            float m = msk_s[bi][(cc & 3) * 16 + ln];
            #pragma unroll
            for (int ct = 0; ct < 2; ++ct)
                #pragma unroll
                for (int reg = 0; reg < 4; ++reg)
                    csum[ct][reg] = fmaf(fmaxf(acc2[ct][reg], 0.f), m, csum[ct][reg]);
        }

        // ---- end of b: row-butterfly reduce, l2norm, store
        if ((cc & 3) == 3) {
            #pragma unroll
            for (int s = 1; s < 16; s <<= 1)
                #pragma unroll
                for (int ct = 0; ct < 2; ++ct)
                    #pragma unroll
                    for (int reg = 0; reg < 4; ++reg)
                        csum[ct][reg] += __shfl_xor(csum[ct][reg], s, 64);
            if (ln == 0) {
                #pragma unroll
                for (int ct = 0; ct < 2; ++ct)
                    #pragma unroll
                    for (int reg = 0; reg < 4; ++reg)
                        redv[w * 32 + ct * 16 + lg * 4 + reg] = csum[ct][reg];
            }
            wg_barrier();
            float v = 0.f;
            if (tid < 128) {
                v = redv[tid] / ncol_s[bi];
                float s2 = v * v;
                #pragma unroll
                for (int sh = 1; sh < 64; sh <<= 1) s2 += __shfl_xor(s2, sh, 64);
                if (l == 0) redq[w] = s2;
            }
            wg_barrier();
            if (tid < 128) {
                float inv = rsqrtf(fmaxf(redq[0] + redq[1], 1e-12f));
                te_out[(size_t)(bb0 + bi) * D_ + tid] = v * inv;
            }
            #pragma unroll
            for (int ct = 0; ct < 2; ++ct)
                #pragma unroll
                for (int reg = 0; reg < 4; ++reg)
                    csum[ct][reg] = 0.f;
        }

        wg_barrier_vm();   // next chunk landed & visible to all waves
    }
}

// ---------------------------------------------------------------------------
// LSTM (round-5 structure, unchanged): 256 blocks x 512 threads, 16 rows/blk,
// depth-1 x prefetch, raw barriers, weights pinned resident (~204 regs ->
// 2 waves/SIMD, the whole 8-wave block fits).
// ---------------------------------------------------------------------------
__global__ __launch_bounds__(512) __attribute__((amdgpu_waves_per_eu(1, 2)))
void lstm_kernel(
    const float* __restrict__ q, const int* __restrict__ lengths,
    const short* __restrict__ WTl, const float* __restrict__ bl,
    float* __restrict__ qe_out)
{
    const int tid = threadIdx.x;
    const int b0  = blockIdx.x * 16;
    const int w   = tid >> 6;
    const int l   = tid & 63;
    const int lg  = l >> 4;
    const int ln  = l & 15;       // batch row within block
    const int d0  = w * 16 + lg * 4;

    __shared__ __align__(16) short xh[2][16 * 256];  // 2 x 8 KB, swizzled
    __shared__ float red8[8][16];

    bf16x8 wf[4][8];
    #pragma unroll
    for (int g = 0; g < 4; ++g)
        #pragma unroll
        for (int ks = 0; ks < 8; ++ks)
            wf[g][ks] = *(const bf16x8*)&WTl[(w * 64 + g * 16 + ln) * 256 + ks * 32 + lg * 8];
    float bias[4][4];
    #pragma unroll
    for (int g = 0; g < 4; ++g)
        #pragma unroll
        for (int reg = 0; reg < 4; ++reg)
            bias[g][reg] = bl[g * 128 + d0 + reg];
    #pragma unroll
    for (int g = 0; g < 4; ++g) {
        #pragma unroll
        for (int ks = 0; ks < 8; ++ks) KEEP(wf[g][ks]);
        #pragma unroll
        for (int reg = 0; reg < 4; ++reg) KEEP(bias[g][reg]);
    }

    float creg[4] = {0.f, 0.f, 0.f, 0.f};
    float hreg[4] = {0.f, 0.f, 0.f, 0.f};
    const int len = lengths[b0 + ln];
    const int sr = tid >> 5, sc = tid & 31;

    // prefetch x_0
    float4 qv = *(const float4*)&q[((size_t)(b0 + sr) * LQ_ + 0) * D_ + sc * 4];

    for (int t = 0; t < LQ_; ++t) {
        char* buf = (char*)xh[t & 1];
        // stage x_t from prefetched regs
        uint2 px; px.x = cvt_pk_bf16(qv.x, qv.y); px.y = cvt_pk_bf16(qv.z, qv.w);
        *(uint2*)(buf + sr * 512 + ((sc * 8) ^ ((sr & 7) << 4))) = px;
        // write h(t-1)
        uint2 ph; ph.x = cvt_pk_bf16(hreg[0], hreg[1]); ph.y = cvt_pk_bf16(hreg[2], hreg[3]);
        *(uint2*)(buf + ln * 512 + ((256 + d0 * 2) ^ ((ln & 7) << 4))) = ph;
        // prefetch x_{t+1}: stays in flight across the raw barrier + MFMA
        if (t + 1 < LQ_)
            qv = *(const float4*)&q[((size_t)(b0 + sr) * LQ_ + (t + 1)) * D_ + sc * 4];
        wg_barrier();

        f32x4 acc[4];
        #pragma unroll
        for (int g = 0; g < 4; ++g)
            acc[g] = (f32x4){bias[g][0], bias[g][1], bias[g][2], bias[g][3]};
        #pragma unroll
        for (int ks = 0; ks < 8; ++ks) {
            bf16x8 xf = *(const bf16x8*)(buf + ln * 512 + ((ks * 64 + lg * 16) ^ ((ln & 7) << 4)));
            #pragma unroll
            for (int g = 0; g < 4; ++g)
                acc[g] = __builtin_amdgcn_mfma_f32_16x16x32_bf16(wf[g][ks], xf, acc[g], 0, 0, 0);
        }

        bool live = (t < len);
        #pragma unroll
        for (int reg = 0; reg < 4; ++reg) {
            float iv = sigm(acc[0][reg]);
            float fv = sigm(acc[1][reg]);
            float gv = fmaxf(acc[2][reg], 0.f);
            float ov = sigm(acc[3][reg]);
            float cn = fmaf(fv, creg[reg], iv * gv);
            float hn = ov * fmaxf(cn, 0.f);
            if (live) { creg[reg] = cn; hreg[reg] = hn; }
        }
    }

    // l2norm per batch row
    float sq = 0.f;
    #pragma unroll
    for (int reg = 0; reg < 4; ++reg) sq = fmaf(hreg[reg], hreg[reg], sq);
    sq += __shfl_xor(sq, 16, 64);
    sq += __shfl_xor(sq, 32, 64);
    if (l < 16) red8[w][ln] = sq;
    wg_barrier();
    float tot = 0.f;
    #pragma unroll
    for (int ww = 0; ww < 8; ++ww) tot += red8[ww][ln];
    float inv = rsqrtf(fmaxf(tot, 1e-12f));
    float4 o;
    o.x = hreg[0] * inv; o.y = hreg[1] * inv; o.z = hreg[2] * inv; o.w = hreg[3] * inv;
    *(float4*)&qe_out[(size_t)(b0 + ln) * D_ + d0] = o;
}

// ---------------------------------------------------------------------------
// Loss: 64 blocks x 64 threads, 1 sample per thread.
// ---------------------------------------------------------------------------
__global__ __launch_bounds__(64) void loss_kernel(
    const float* __restrict__ te, const float* __restrict__ qe,
    const float* __restrict__ labels, float* __restrict__ partial)
{
    const int tid = threadIdx.x;
    const int b   = blockIdx.x * 64 + tid;
    float dsum = 0.f;
    #pragma unroll 8
    for (int k4 = 0; k4 < 32; ++k4) {
        float4 a = *(const float4*)&qe[(size_t)b * D_ + k4 * 4];
        float4 c = *(const float4*)&te[(size_t)b * D_ + k4 * 4];
        float dx = a.x - c.x, dy = a.y - c.y, dz = a.z - c.z, dw = a.w - c.w;
        dsum += dx * dx + dy * dy + dz * dz + dw * dw;
    }
    float lab = labels[b];
    float ds  = sqrtf(dsum);
    float ml  = fmaxf(0.f, 1.f - ds);
    float loss = lab * dsum + (1.f - lab) * ml * ml;
    #pragma unroll
    for (int s = 32; s > 0; s >>= 1) loss += __shfl_xor(loss, s, 64);
    if (tid == 0) partial[blockIdx.x] = loss;
}

__global__ void final_kernel(const float* __restrict__ partial, float* __restrict__ out)
{
    const int tid = threadIdx.x;   // 64 threads
    float v = partial[tid];
    #pragma unroll
    for (int s = 32; s > 0; s >>= 1) v += __shfl_xor(v, s, 64);
    if (tid == 0) out[0] = 0.5f * v / (float)B_;
}

// ---------------------------------------------------------------------------
extern "C" void kernel_launch(void* const* d_in, const int* in_sizes, int n_in,
                              void* d_out, int out_size, void* d_ws, size_t ws_size,
                              hipStream_t stream)
{
    const float* q      = (const float*)d_in[0];
    const int*   qlen   = (const int*)d_in[1];
    const float* header = (const float*)d_in[2];
    const float* tword  = (const float*)d_in[3];
    const int*   ncols  = (const int*)d_in[4];
    const float* masks  = (const float*)d_in[5];
    const float* labels = (const float*)d_in[6];
    const float* W1     = (const float*)d_in[7];
    const float* b1     = (const float*)d_in[8];
    const float* W2     = (const float*)d_in[9];
    const float* b2     = (const float*)d_in[10];
    const float* Wx     = (const float*)d_in[11];
    const float* Wh     = (const float*)d_in[12];
    const float* bl     = (const float*)d_in[13];
    float* out = (float*)d_out;

    float* te      = (float*)d_ws;
    float* qe      = te + (size_t)B_ * D_;
    float* partial = qe + (size_t)B_ * D_;
    short* W1T     = (short*)(partial + 64);          // 192*256
    short* W2T     = W1T + 192 * 256;                 // 128*192
    short* WTl     = W2T + 128 * 192;                 // 512*256

    prep_kernel<<<512, 256, 0, stream>>>(W1, W2, Wx, Wh, W1T, W2T, WTl);
    table_kernel<<<B_ / 4, 256, 0, stream>>>(header, tword, masks, ncols, W1T, b1, W2T, b2, te);
    lstm_kernel<<<B_ / 16, 512, 0, stream>>>(q, qlen, WTl, bl, qe);
    loss_kernel<<<B_ / 64, 64, 0, stream>>>(te, qe, labels, partial);
    final_kernel<<<1, 64, 0, stream>>>(partial, out);
}

// Round 10
// 152.486 us; speedup vs baseline: 1.2568x; 1.0941x over previous
//
#include <hip/hip_runtime.h>
#include <math.h>

#define B_  4096
#define C_  64
#define LQ_ 32
#define D_  128
#define H_  192

typedef __attribute__((ext_vector_type(8))) short bf16x8;
typedef __attribute__((ext_vector_type(4))) float f32x4;

#define KEEP(x) asm volatile("" : "+v"(x))

__device__ inline unsigned cvt_pk_bf16(float lo, float hi) {
    unsigned r;
    asm("v_cvt_pk_bf16_f32 %0, %1, %2" : "=v"(r) : "v"(lo), "v"(hi));
    return r;
}
__device__ inline short f2b(float x) { return (short)(cvt_pk_bf16(x, x) & 0xffff); }
__device__ inline float sigm(float x) { return 1.f / (1.f + __expf(-x)); }

// Raw barrier: waits LDS ops only; leaves global loads / LDS-DMA in flight.
__device__ inline void wg_barrier() {
    asm volatile("s_waitcnt lgkmcnt(0)" ::: "memory");
    __builtin_amdgcn_s_barrier();
    asm volatile("" ::: "memory");
}

// ---------------------------------------------------------------------------
// Prep: transpose + convert weights to bf16.
// ---------------------------------------------------------------------------
__global__ __launch_bounds__(256) void prep_kernel(
    const float* __restrict__ W1, const float* __restrict__ W2,
    const float* __restrict__ Wx, const float* __restrict__ Wh,
    short* __restrict__ W1T, short* __restrict__ W2T, short* __restrict__ WTl)
{
    int idx = blockIdx.x * 256 + threadIdx.x;   // 0 .. 131071
    if (idx < 192 * 256) {
        int j = idx >> 8, k = idx & 255;
        W1T[idx] = f2b(W1[k * H_ + j]);
    }
    if (idx < 128 * 192) {
        int j = idx / 192, k = idx - j * 192;
        W2T[idx] = f2b(W2[k * D_ + j]);
    }
    if (idx < 512 * 256) {
        int p = idx >> 8, k = idx & 255;
        int w = p >> 6, g = (p >> 4) & 3, jj = p & 15;
        int jo = g * 128 + w * 16 + jj;
        float v = (k < 128) ? Wx[k * 512 + jo] : Wh[(k - 128) * 512 + jo];
        WTl[idx] = f2b(v);
    }
}

// ---------------------------------------------------------------------------
// Table encoder v10: T4-correct pipeline.
//  - 3-buffer flat32, DEPTH-2 global_load_lds DMA, counted vmcnt(4) at body
//    end (never drain to 0 in the loop; chunk c+1 landed a full body ago).
//  - per-b reductions: barrier-free csum_s flush in-loop, single epilogue.
//  - W1+bias1 pinned resident; W2/bias2 streamed from L2 per body.
// 1024 blocks x 256 thr (4 waves), 4 b's/block, 16-row chunks.
// ---------------------------------------------------------------------------
__global__ __launch_bounds__(256, 2)
void table_kernel(
    const float* __restrict__ header, const float* __restrict__ tword,
    const float* __restrict__ masks, const int* __restrict__ num_cols,
    const short* __restrict__ W1T, const float* __restrict__ b1,
    const short* __restrict__ W2T, const float* __restrict__ b2,
    float* __restrict__ te_out)
{
    const int bb0 = blockIdx.x * 4;
    const int tid = threadIdx.x;
    const int w   = tid >> 6;      // 0..3: column-group wave
    const int l   = tid & 63;
    const int lg  = l >> 4;
    const int ln  = l & 15;

    __shared__ __align__(16) float flat32[3][16 * 256];  // 3 x 16 KB (fp32)
    __shared__ __align__(16) short h_s[16 * 192];        // 6 KB bf16, swizzled
    __shared__ float msk_s[4][64];                       // 1 KB
    __shared__ float ncol_s[4];
    __shared__ float csum_s[4][128];                     // 2 KB
    __shared__ float redq[2][4];

    // ---- resident W1 + bias1 (pinned)
    bf16x8 bw1[3][8];
    float  bias1[3][4];
    #pragma unroll
    for (int ct = 0; ct < 3; ++ct) {
        int j = w * 48 + ct * 16 + ln;
        #pragma unroll
        for (int ks = 0; ks < 8; ++ks)
            bw1[ct][ks] = *(const bf16x8*)&W1T[j * 256 + ks * 32 + lg * 8];
        #pragma unroll
        for (int reg = 0; reg < 4; ++reg)
            bias1[ct][reg] = b1[w * 48 + ct * 16 + lg * 4 + reg];
    }
    #pragma unroll
    for (int ct = 0; ct < 3; ++ct) {
        #pragma unroll
        for (int ks = 0; ks < 8; ++ks) KEEP(bw1[ct][ks]);
        #pragma unroll
        for (int reg = 0; reg < 4; ++reg) KEEP(bias1[ct][reg]);
    }

    // ---- preload masks + num_cols for the 4 b's
    ((float*)msk_s)[tid] = masks[(size_t)bb0 * C_ + tid];
    if (tid < 4) ncol_s[tid] = (float)num_cols[bb0 + tid];

    // ---- async DMA: chunk = 16 rows x 1 KB; wave w issues rows w*4..+3.
    //      Linear LDS dest; source carries the inverse swizzle (rule #21).
    auto stage_issue = [&](int cc, int buf) {
        int b    = bb0 + (cc >> 2);
        int row0 = (cc & 3) * 16;
        #pragma unroll
        for (int i = 0; i < 4; ++i) {
            int r = w * 4 + i;                          // wave-uniform
            int p = ((l * 16) ^ ((r & 7) << 4)) >> 2;   // f32 col, mult of 4
            const float* srcp = (p < 128)
                ? header + ((size_t)b * C_ + row0 + r) * D_ + p
                : tword  + ((size_t)b * C_ + row0 + r) * D_ + (p - 128);
            __builtin_amdgcn_global_load_lds(
                (const __attribute__((address_space(1))) unsigned*)srcp,
                (__attribute__((address_space(3))) unsigned*)&flat32[buf][r * 256],
                16, 0, 0);
        }
    };

    stage_issue(0, 0);
    stage_issue(1, 1);
    __syncthreads();          // prologue-only full drain: chunks 0,1 landed

    float csum[2][4] = {{0.f, 0.f, 0.f, 0.f}, {0.f, 0.f, 0.f, 0.f}};
    const int swz = (ln & 7) << 4;

    #pragma unroll 1
    for (int cc = 0; cc < 16; ++cc) {
        const int bi = cc >> 2;

        // ---- stream W2/bias2 (L2) first, then issue DMA for chunk c+2
        bf16x8 w2f[2][6];
        #pragma unroll
        for (int ct = 0; ct < 2; ++ct)
            #pragma unroll
            for (int ks = 0; ks < 6; ++ks)
                w2f[ct][ks] = *(const bf16x8*)&W2T[(w * 32 + ct * 16 + ln) * 192 + ks * 32 + lg * 8];
        float4 b2v[2];
        #pragma unroll
        for (int ct = 0; ct < 2; ++ct)
            b2v[ct] = *(const float4*)&b2[w * 32 + ct * 16 + lg * 4];
        if (cc + 2 < 16) stage_issue(cc + 2, (cc + 2) % 3);

        // ---- GEMM1: bf16-ify B-frags from fp32 LDS, 24 MFMA vs resident W1
        {
            const char* fb = (const char*)flat32[cc % 3] + ln * 1024;
            f32x4 acc[3];
            #pragma unroll
            for (int ct = 0; ct < 3; ++ct)
                acc[ct] = (f32x4){bias1[ct][0], bias1[ct][1], bias1[ct][2], bias1[ct][3]};
            #pragma unroll
            for (int ks = 0; ks < 8; ++ks) {
                int base = ks * 128 + lg * 32;
                f32x4 a0 = *(const f32x4*)(fb + ((base)      ^ swz));
                f32x4 a1 = *(const f32x4*)(fb + ((base + 16) ^ swz));
                unsigned uu[4];
                uu[0] = cvt_pk_bf16(a0[0], a0[1]);
                uu[1] = cvt_pk_bf16(a0[2], a0[3]);
                uu[2] = cvt_pk_bf16(a1[0], a1[1]);
                uu[3] = cvt_pk_bf16(a1[2], a1[3]);
                bf16x8 bfrag = *(bf16x8*)uu;
                #pragma unroll
                for (int ct = 0; ct < 3; ++ct)
                    acc[ct] = __builtin_amdgcn_mfma_f32_16x16x32_bf16(bw1[ct][ks], bfrag, acc[ct], 0, 0, 0);
            }
            #pragma unroll
            for (int ct = 0; ct < 3; ++ct) {
                int col0 = w * 48 + ct * 16 + lg * 4;
                uint2 hp;
                hp.x = cvt_pk_bf16(fmaxf(acc[ct][0], 0.f), fmaxf(acc[ct][1], 0.f));
                hp.y = cvt_pk_bf16(fmaxf(acc[ct][2], 0.f), fmaxf(acc[ct][3], 0.f));
                *(uint2*)((char*)h_s + ln * 384 + ((col0 * 2) ^ swz)) = hp;
            }
        }
        wg_barrier();   // h ready; DMAs stay in flight

        // ---- GEMM2 (streamed W2) + fused mask*column-sum
        {
            f32x4 acc2[2];
            #pragma unroll
            for (int ct = 0; ct < 2; ++ct)
                acc2[ct] = (f32x4){b2v[ct].x, b2v[ct].y, b2v[ct].z, b2v[ct].w};
            #pragma unroll
            for (int ks = 0; ks < 6; ++ks) {
                bf16x8 a = *(const bf16x8*)((char*)h_s + ln * 384 + ((ks * 64 + lg * 16) ^ swz));
                #pragma unroll
                for (int ct = 0; ct < 2; ++ct)
                    acc2[ct] = __builtin_amdgcn_mfma_f32_16x16x32_bf16(w2f[ct][ks], a, acc2[ct], 0, 0, 0);
            }
            float m = msk_s[bi][(cc & 3) * 16 + ln];
            #pragma unroll
            for (int ct = 0; ct < 2; ++ct)
                #pragma unroll
                for (int reg = 0; reg < 4; ++reg)
                    csum[ct][reg] = fmaf(fmaxf(acc2[ct][reg], 0.f), m, csum[ct][reg]);
        }

        // ---- end of b: butterfly + barrier-free flush to csum_s
        if ((cc & 3) == 3) {
            #pragma unroll
            for (int s = 1; s < 16; s <<= 1)
                #pragma unroll
                for (int ct = 0; ct < 2; ++ct)
                    #pragma unroll
                    for (int reg = 0; reg < 4; ++reg)
                        csum[ct][reg] += __shfl_xor(csum[ct][reg], s, 64);
            if (ln == 0) {
                #pragma unroll
                for (int ct = 0; ct < 2; ++ct)
                    #pragma unroll
                    for (int reg = 0; reg < 4; ++reg)
                        csum_s[bi][w * 32 + ct * 16 + lg * 4 + reg] = csum[ct][reg];
            }
            #pragma unroll
            for (int ct = 0; ct < 2; ++ct)
                #pragma unroll
                for (int reg = 0; reg < 4; ++reg)
                    csum[ct][reg] = 0.f;
        }

        // ---- end of body: counted vmcnt (T4) + raw barrier
        if (cc < 14) {
            asm volatile("s_waitcnt vmcnt(4) lgkmcnt(0)" ::: "memory");
            __builtin_amdgcn_s_barrier();
            asm volatile("" ::: "memory");
        } else if (cc == 14) {
            asm volatile("s_waitcnt vmcnt(0) lgkmcnt(0)" ::: "memory");
            __builtin_amdgcn_s_barrier();
            asm volatile("" ::: "memory");
        }
    }

    // ---- epilogue: all 4 b's (csum_s flushed in-loop)
    __syncthreads();
    if (tid < 128) {
        float vv[4];
        #pragma unroll
        for (int bi = 0; bi < 4; ++bi) {
            float v = csum_s[bi][tid] / ncol_s[bi];
            vv[bi] = v;
            float s2 = v * v;
            #pragma unroll
            for (int sh = 1; sh < 64; sh <<= 1) s2 += __shfl_xor(s2, sh, 64);
            if (l == 0) redq[w][bi] = s2;
        }
        __builtin_amdgcn_s_barrier();
        #pragma unroll
        for (int bi = 0; bi < 4; ++bi) {
            float inv = rsqrtf(fmaxf(redq[0][bi] + redq[1][bi], 1e-12f));
            te_out[(size_t)(bb0 + bi) * D_ + tid] = vv[bi] * inv;
        }
    }
}

// ---------------------------------------------------------------------------
// LSTM (round-5 structure, unchanged — runs at its MFMA floor).
// ---------------------------------------------------------------------------
__global__ __launch_bounds__(512) __attribute__((amdgpu_waves_per_eu(1, 2)))
void lstm_kernel(
    const float* __restrict__ q, const int* __restrict__ lengths,
    const short* __restrict__ WTl, const float* __restrict__ bl,
    float* __restrict__ qe_out)
{
    const int tid = threadIdx.x;
    const int b0  = blockIdx.x * 16;
    const int w   = tid >> 6;
    const int l   = tid & 63;
    const int lg  = l >> 4;
    const int ln  = l & 15;       // batch row within block
    const int d0  = w * 16 + lg * 4;

    __shared__ __align__(16) short xh[2][16 * 256];  // 2 x 8 KB, swizzled
    __shared__ float red8[8][16];

    bf16x8 wf[4][8];
    #pragma unroll
    for (int g = 0; g < 4; ++g)
        #pragma unroll
        for (int ks = 0; ks < 8; ++ks)
            wf[g][ks] = *(const bf16x8*)&WTl[(w * 64 + g * 16 + ln) * 256 + ks * 32 + lg * 8];
    float bias[4][4];
    #pragma unroll
    for (int g = 0; g < 4; ++g)
        #pragma unroll
        for (int reg = 0; reg < 4; ++reg)
            bias[g][reg] = bl[g * 128 + d0 + reg];
    #pragma unroll
    for (int g = 0; g < 4; ++g) {
        #pragma unroll
        for (int ks = 0; ks < 8; ++ks) KEEP(wf[g][ks]);
        #pragma unroll
        for (int reg = 0; reg < 4; ++reg) KEEP(bias[g][reg]);
    }

    float creg[4] = {0.f, 0.f, 0.f, 0.f};
    float hreg[4] = {0.f, 0.f, 0.f, 0.f};
    const int len = lengths[b0 + ln];
    const int sr = tid >> 5, sc = tid & 31;

    // prefetch x_0
    float4 qv = *(const float4*)&q[((size_t)(b0 + sr) * LQ_ + 0) * D_ + sc * 4];

    for (int t = 0; t < LQ_; ++t) {
        char* buf = (char*)xh[t & 1];
        // stage x_t from prefetched regs
        uint2 px; px.x = cvt_pk_bf16(qv.x, qv.y); px.y = cvt_pk_bf16(qv.z, qv.w);
        *(uint2*)(buf + sr * 512 + ((sc * 8) ^ ((sr & 7) << 4))) = px;
        // write h(t-1)
        uint2 ph; ph.x = cvt_pk_bf16(hreg[0], hreg[1]); ph.y = cvt_pk_bf16(hreg[2], hreg[3]);
        *(uint2*)(buf + ln * 512 + ((256 + d0 * 2) ^ ((ln & 7) << 4))) = ph;
        // prefetch x_{t+1}: stays in flight across the raw barrier + MFMA
        if (t + 1 < LQ_)
            qv = *(const float4*)&q[((size_t)(b0 + sr) * LQ_ + (t + 1)) * D_ + sc * 4];
        wg_barrier();

        f32x4 acc[4];
        #pragma unroll
        for (int g = 0; g < 4; ++g)
            acc[g] = (f32x4){bias[g][0], bias[g][1], bias[g][2], bias[g][3]};
        #pragma unroll
        for (int ks = 0; ks < 8; ++ks) {
            bf16x8 xf = *(const bf16x8*)(buf + ln * 512 + ((ks * 64 + lg * 16) ^ ((ln & 7) << 4)));
            #pragma unroll
            for (int g = 0; g < 4; ++g)
                acc[g] = __builtin_amdgcn_mfma_f32_16x16x32_bf16(wf[g][ks], xf, acc[g], 0, 0, 0);
        }

        bool live = (t < len);
        #pragma unroll
        for (int reg = 0; reg < 4; ++reg) {
            float iv = sigm(acc[0][reg]);
            float fv = sigm(acc[1][reg]);
            float gv = fmaxf(acc[2][reg], 0.f);
            float ov = sigm(acc[3][reg]);
            float cn = fmaf(fv, creg[reg], iv * gv);
            float hn = ov * fmaxf(cn, 0.f);
            if (live) { creg[reg] = cn; hreg[reg] = hn; }
        }
    }

    // l2norm per batch row
    float sq = 0.f;
    #pragma unroll
    for (int reg = 0; reg < 4; ++reg) sq = fmaf(hreg[reg], hreg[reg], sq);
    sq += __shfl_xor(sq, 16, 64);
    sq += __shfl_xor(sq, 32, 64);
    if (l < 16) red8[w][ln] = sq;
    wg_barrier();
    float tot = 0.f;
    #pragma unroll
    for (int ww = 0; ww < 8; ++ww) tot += red8[ww][ln];
    float inv = rsqrtf(fmaxf(tot, 1e-12f));
    float4 o;
    o.x = hreg[0] * inv; o.y = hreg[1] * inv; o.z = hreg[2] * inv; o.w = hreg[3] * inv;
    *(float4*)&qe_out[(size_t)(b0 + ln) * D_ + d0] = o;
}

// ---------------------------------------------------------------------------
// Loss: 64 blocks x 64 threads, 1 sample per thread.
// ---------------------------------------------------------------------------
__global__ __launch_bounds__(64) void loss_kernel(
    const float* __restrict__ te, const float* __restrict__ qe,
    const float* __restrict__ labels, float* __restrict__ partial)
{
    const int tid = threadIdx.x;
    const int b   = blockIdx.x * 64 + tid;
    float dsum = 0.f;
    #pragma unroll 8
    for (int k4 = 0; k4 < 32; ++k4) {
        float4 a = *(const float4*)&qe[(size_t)b * D_ + k4 * 4];
        float4 c = *(const float4*)&te[(size_t)b * D_ + k4 * 4];
        float dx = a.x - c.x, dy = a.y - c.y, dz = a.z - c.z, dw = a.w - c.w;
        dsum += dx * dx + dy * dy + dz * dz + dw * dw;
    }
    float lab = labels[b];
    float ds  = sqrtf(dsum);
    float ml  = fmaxf(0.f, 1.f - ds);
    float loss = lab * dsum + (1.f - lab) * ml * ml;
    #pragma unroll
    for (int s = 32; s > 0; s >>= 1) loss += __shfl_xor(loss, s, 64);
    if (tid == 0) partial[blockIdx.x] = loss;
}

__global__ void final_kernel(const float* __restrict__ partial, float* __restrict__ out)
{
    const int tid = threadIdx.x;   // 64 threads
    float v = partial[tid];
    #pragma unroll
    for (int s = 32; s > 0; s >>= 1) v += __shfl_xor(v, s, 64);
    if (tid == 0) out[0] = 0.5f * v / (float)B_;
}

// ---------------------------------------------------------------------------
extern "C" void kernel_launch(void* const* d_in, const int* in_sizes, int n_in,
                              void* d_out, int out_size, void* d_ws, size_t ws_size,
                              hipStream_t stream)
{
    const float* q      = (const float*)d_in[0];
    const int*   qlen   = (const int*)d_in[1];
    const float* header = (const float*)d_in[2];
    const float* tword  = (const float*)d_in[3];
    const int*   ncols  = (const int*)d_in[4];
    const float* masks  = (const float*)d_in[5];
    const float* labels = (const float*)d_in[6];
    const float* W1     = (const float*)d_in[7];
    const float* b1     = (const float*)d_in[8];
    const float* W2     = (const float*)d_in[9];
    const float* b2     = (const float*)d_in[10];
    const float* Wx     = (const float*)d_in[11];
    const float* Wh     = (const float*)d_in[12];
    const float* bl     = (const float*)d_in[13];
    float* out = (float*)d_out;

    float* te      = (float*)d_ws;
    float* qe      = te + (size_t)B_ * D_;
    float* partial = qe + (size_t)B_ * D_;
    short* W1T     = (short*)(partial + 64);          // 192*256
    short* W2T     = W1T + 192 * 256;                 // 128*192
    short* WTl     = W2T + 128 * 192;                 // 512*256

    prep_kernel<<<512, 256, 0, stream>>>(W1, W2, Wx, Wh, W1T, W2T, WTl);
    table_kernel<<<B_ / 4, 256, 0, stream>>>(header, tword, masks, ncols, W1T, b1, W2T, b2, te);
    lstm_kernel<<<B_ / 16, 512, 0, stream>>>(q, qlen, WTl, bl, qe);
    loss_kernel<<<B_ / 64, 64, 0, stream>>>(te, qe, labels, partial);
    final_kernel<<<1, 64, 0, stream>>>(partial, out);
}